// Round 1
// baseline (278.288 us; speedup 1.0000x reference)
//
#include <hip/hip_runtime.h>
#include <math.h>

#define FHH 16
#define FWW 44
#define DB 41
#define NCAM 6
#define CIN 512
#define NC 128
#define NPIX (FHH*FWW)            // 704
#define TOTPIX (NCAM*NPIX)        // 4224
#define NPTS (NCAM*DB*NPIX)       // 173184
#define NSPAT (128*128)           // 16384

// workspace float offsets
#define OFF_MATS   0
#define OFF_FEATD  256                                  // 6*41*704 = 173184
#define OFF_CFEATT (OFF_FEATD + NCAM*DB*NPIX)           // 173440; 6*704*128 = 540672
#define OFF_BINS   (OFF_CFEATT + NCAM*NPIX*NC)          // 714112; 173184 ints
#define OFF_TMP    (OFF_BINS + NPTS)                    // 887296; 16384*128 floats

// ---- exact fp32 LAPACK-emulating 3x3 inverse (sgetf2 + strti2 + sgetri) ----
__device__ void lapack_inv3(const float* src, float* dst) {
    float A[3][3]; int piv[3];
    for (int i = 0; i < 3; i++)
        for (int j = 0; j < 3; j++) A[i][j] = src[i*3+j];
    // sgetf2 with partial pivoting (reciprocal-scale path)
    for (int j = 0; j < 3; j++) {
        int p = j; float mx = fabsf(A[j][j]);
        for (int i = j+1; i < 3; i++) { float v = fabsf(A[i][j]); if (v > mx) { mx = v; p = i; } }
        piv[j] = p;
        if (p != j) for (int k = 0; k < 3; k++) { float t = A[j][k]; A[j][k] = A[p][k]; A[p][k] = t; }
        float r = __fdiv_rn(1.0f, A[j][j]);
        for (int i = j+1; i < 3; i++) A[i][j] = __fmul_rn(A[i][j], r);
        for (int i = j+1; i < 3; i++)
            for (int k = j+1; k < 3; k++)
                A[i][k] = __fsub_rn(A[i][k], __fmul_rn(A[i][j], A[j][k]));
    }
    // strti2: invert U in place (upper, non-unit)
    for (int j = 0; j < 3; j++) {
        float ajj = __fdiv_rn(1.0f, A[j][j]);
        A[j][j] = ajj;
        float najj = -ajj;
        // strmv: x(0:j-1) = U(0:j-1,0:j-1)*x, column-oriented
        for (int k = 0; k < j; k++) {
            float temp = A[k][j];
            for (int i = 0; i < k; i++) A[i][j] = __fadd_rn(A[i][j], __fmul_rn(temp, A[i][k]));
            A[k][j] = __fmul_rn(temp, A[k][k]);
        }
        for (int i = 0; i < j; i++) A[i][j] = __fmul_rn(A[i][j], najj);
    }
    // sgetri solve step: inv(A)*L = inv(U)
    float work[3];
    for (int j = 2; j >= 0; j--) {
        for (int i = j+1; i < 3; i++) { work[i] = A[i][j]; A[i][j] = 0.0f; }
        for (int k = j+1; k < 3; k++) {
            float t = -work[k];
            for (int i = 0; i < 3; i++) A[i][j] = __fadd_rn(A[i][j], __fmul_rn(t, A[i][k]));
        }
    }
    // reversed column swaps
    for (int j = 2; j >= 0; j--) {
        int p = piv[j];
        if (p != j) for (int i = 0; i < 3; i++) { float t = A[i][j]; A[i][j] = A[i][p]; A[i][p] = t; }
    }
    for (int i = 0; i < 3; i++)
        for (int j = 0; j < 3; j++) dst[i*3+j] = A[i][j];
}

// ---- per-camera: M = rots @ inv(intrins), P = inv(post_rots) ----
__global__ void prep_kernel(const float* __restrict__ rots, const float* __restrict__ intrins,
                            const float* __restrict__ post_rots, float* __restrict__ mats) {
    int n = threadIdx.x;
    if (n >= NCAM) return;
    float invK[9], invP[9], M[9];
    lapack_inv3(intrins + n*9, invK);
    lapack_inv3(post_rots + n*9, invP);
    for (int i = 0; i < 3; i++)
        for (int k = 0; k < 3; k++) {
            float s = __fmul_rn(rots[n*9 + i*3 + 0], invK[0*3 + k]);
            s = __fadd_rn(s, __fmul_rn(rots[n*9 + i*3 + 1], invK[1*3 + k]));
            s = __fadd_rn(s, __fmul_rn(rots[n*9 + i*3 + 2], invK[2*3 + k]));
            M[i*3 + k] = s;
        }
    for (int i = 0; i < 9; i++) { mats[n*18 + i] = M[i]; mats[n*18 + 9 + i] = invP[i]; }
}

// ---- per-point voxel bin (exact fp32 replica of the np geometry path) ----
__global__ void bins_kernel(const float* __restrict__ trans, const float* __restrict__ post_trans,
                            const float* __restrict__ mats, int* __restrict__ bins) {
    int p = blockIdx.x * 256 + threadIdx.x;
    if (p >= NPTS) return;
    int n   = p / (DB*NPIX);
    int rem = p % (DB*NPIX);
    int d   = rem / NPIX;
    int pix = rem % NPIX;
    int h = pix / FWW, w = pix % FWW;
    // np.linspace: computed in float64, cast to float32
    float xs = (float)((double)w * (703.0/43.0));
    float ys = (float)((double)h * (255.0/15.0));
    float ds = 4.0f + (float)d;
    const float* M = mats + n*18;
    const float* P = mats + n*18 + 9;
    float px = __fsub_rn(xs, post_trans[n*3+0]);
    float py = __fsub_rn(ys, post_trans[n*3+1]);
    float pz = __fsub_rn(ds, post_trans[n*3+2]);
    float q0 = __fadd_rn(__fadd_rn(__fmul_rn(P[0],px), __fmul_rn(P[1],py)), __fmul_rn(P[2],pz));
    float q1 = __fadd_rn(__fadd_rn(__fmul_rn(P[3],px), __fmul_rn(P[4],py)), __fmul_rn(P[5],pz));
    float q2 = __fadd_rn(__fadd_rn(__fmul_rn(P[6],px), __fmul_rn(P[7],py)), __fmul_rn(P[8],pz));
    float r0 = __fmul_rn(q0, q2);
    float r1 = __fmul_rn(q1, q2);
    float r2 = q2;
    float g0 = __fadd_rn(__fadd_rn(__fadd_rn(__fmul_rn(M[0],r0), __fmul_rn(M[1],r1)), __fmul_rn(M[2],r2)), trans[n*3+0]);
    float g1 = __fadd_rn(__fadd_rn(__fadd_rn(__fmul_rn(M[3],r0), __fmul_rn(M[4],r1)), __fmul_rn(M[5],r2)), trans[n*3+1]);
    float g2 = __fadd_rn(__fadd_rn(__fadd_rn(__fmul_rn(M[6],r0), __fmul_rn(M[7],r1)), __fmul_rn(M[8],r2)), trans[n*3+2]);
    const float lox = -50.8f - (0.8f/2.0f);
    const float loy = -50.8f - (0.8f/2.0f);
    const float loz =   0.0f - (20.0f/2.0f);
    int gx = (int)(__fdiv_rn(__fsub_rn(g0, lox), 0.8f));   // trunc toward zero == astype(int32)
    int gy = (int)(__fdiv_rn(__fsub_rn(g1, loy), 0.8f));
    int gz = (int)(__fdiv_rn(__fsub_rn(g2, loz), 20.0f));
    bool ok = (gx >= 0) & (gx < 128) & (gy >= 0) & (gy < 128) & (gz >= 0) & (gz < 1);
    bins[p] = ok ? (gy*128 + gx) : -1;
}

// ---- feat = w_depth @ x + b ; first 41 rows to featd, last 128 transposed ----
__global__ void feat_kernel(const float* __restrict__ x, const float* __restrict__ wd,
                            const float* __restrict__ bd, float* __restrict__ featd,
                            float* __restrict__ cfeatT) {
    int pix = blockIdx.x * 64 + threadIdx.x;   // 11*64 = 704
    int o0  = blockIdx.y * 8;                  // 22 tiles covers 169
    int n   = blockIdx.z;
    const float* xp = x + (size_t)n * CIN * NPIX + pix;
    float acc[8] = {0,0,0,0,0,0,0,0};
    const float* wrow[8];
    #pragma unroll
    for (int k = 0; k < 8; k++) wrow[k] = wd + (size_t)min(o0 + k, 168) * CIN;
    for (int c = 0; c < CIN; c++) {
        float xv = xp[(size_t)c * NPIX];
        #pragma unroll
        for (int k = 0; k < 8; k++) acc[k] = fmaf(wrow[k][c], xv, acc[k]);
    }
    int no = 169 - o0; if (no > 8) no = 8;
    for (int k = 0; k < no; k++) {
        int o = o0 + k;
        float v = __fadd_rn(acc[k], bd[o]);
        if (o < DB) featd[((size_t)n * DB + o) * NPIX + pix] = v;
        else        cfeatT[((size_t)(n * NPIX + pix)) * NC + (o - DB)] = v;
    }
}

// ---- softmax over depth bins, in place ----
__global__ void softmax_kernel(float* __restrict__ featd) {
    int t = blockIdx.x * 256 + threadIdx.x;
    if (t >= TOTPIX) return;
    int n = t / NPIX, pix = t % NPIX;
    float* f = featd + (size_t)n * DB * NPIX + pix;
    float mx = -1e30f;
    float v[DB];
    #pragma unroll
    for (int d = 0; d < DB; d++) { v[d] = f[(size_t)d * NPIX]; mx = fmaxf(mx, v[d]); }
    float s = 0.0f;
    #pragma unroll
    for (int d = 0; d < DB; d++) { v[d] = expf(v[d] - mx); s += v[d]; }
    float inv = __fdiv_rn(1.0f, s);
    #pragma unroll
    for (int d = 0; d < DB; d++) f[(size_t)d * NPIX] = __fmul_rn(v[d], inv);
}

// ---- scatter: one block per (cam,pixel), 128 threads = channels ----
__global__ void scatter_kernel(const float* __restrict__ depth, const float* __restrict__ cfeatT,
                               const int* __restrict__ bins, float* __restrict__ tmp) {
    int t = blockIdx.x;            // 0..TOTPIX-1
    int c = threadIdx.x;           // 0..127
    int n = t / NPIX, pix = t % NPIX;
    float cf = cfeatT[(size_t)t * NC + c];
    const float* dep = depth + (size_t)n * DB * NPIX + pix;
    const int*   bp  = bins  + (size_t)n * DB * NPIX + pix;
    for (int d = 0; d < DB; d++) {
        int s = bp[(size_t)d * NPIX];
        if (s >= 0) {
            float wv = dep[(size_t)d * NPIX];
            atomicAdd(tmp + (size_t)s * NC + c, __fmul_rn(wv, cf));
        }
    }
}

// ---- transpose tmp[s][c] -> out[c][s] ----
__global__ void transpose_kernel(const float* __restrict__ tmp, float* __restrict__ out) {
    __shared__ float tile[32][33];
    int s0 = blockIdx.x * 32;
    int c0 = blockIdx.y * 32;
    int tx = threadIdx.x;   // 32
    int ty = threadIdx.y;   // 8
    #pragma unroll
    for (int i = 0; i < 32; i += 8)
        tile[ty + i][tx] = tmp[(size_t)(s0 + ty + i) * NC + c0 + tx];
    __syncthreads();
    #pragma unroll
    for (int i = 0; i < 32; i += 8)
        out[(size_t)(c0 + ty + i) * NSPAT + s0 + tx] = tile[tx][ty + i];
}

extern "C" void kernel_launch(void* const* d_in, const int* in_sizes, int n_in,
                              void* d_out, int out_size, void* d_ws, size_t ws_size,
                              hipStream_t stream) {
    const float* x          = (const float*)d_in[0];
    const float* rots       = (const float*)d_in[1];
    const float* trans      = (const float*)d_in[2];
    const float* intrins    = (const float*)d_in[3];
    const float* post_rots  = (const float*)d_in[4];
    const float* post_trans = (const float*)d_in[5];
    const float* w_depth    = (const float*)d_in[6];
    const float* b_depth    = (const float*)d_in[7];
    float* out = (float*)d_out;
    float* ws  = (float*)d_ws;

    float* mats   = ws + OFF_MATS;
    float* featd  = ws + OFF_FEATD;
    float* cfeatT = ws + OFF_CFEATT;
    int*   bins   = (int*)(ws + OFF_BINS);
    float* tmp    = ws + OFF_TMP;

    hipMemsetAsync(tmp, 0, (size_t)NSPAT * NC * sizeof(float), stream);
    prep_kernel<<<1, 64, 0, stream>>>(rots, intrins, post_rots, mats);
    bins_kernel<<<(NPTS + 255) / 256, 256, 0, stream>>>(trans, post_trans, mats, bins);
    feat_kernel<<<dim3(11, 22, NCAM), 64, 0, stream>>>(x, w_depth, b_depth, featd, cfeatT);
    softmax_kernel<<<(TOTPIX + 255) / 256, 256, 0, stream>>>(featd);
    scatter_kernel<<<TOTPIX, NC, 0, stream>>>(featd, cfeatT, bins, tmp);
    transpose_kernel<<<dim3(NSPAT / 32, NC / 32), dim3(32, 8), 0, stream>>>(tmp, out);
}

// Round 2
// 261.089 us; speedup vs baseline: 1.0659x; 1.0659x over previous
//
#include <hip/hip_runtime.h>
#include <math.h>

#define FHH 16
#define FWW 44
#define DB 41
#define NCAM 6
#define CIN 512
#define NC 128
#define NPIX (FHH*FWW)            // 704
#define TOTPIX (NCAM*NPIX)        // 4224
#define NPTS (NCAM*DB*NPIX)       // 173184
#define NSPAT (128*128)           // 16384

// workspace float offsets
#define OFF_MATS   0                                    // 256
#define OFF_FEATD  256                                  // 173184
#define OFF_CFEATT (OFF_FEATD + NCAM*DB*NPIX)           // 173440 ; 540672
#define OFF_BINS   (OFF_CFEATT + NCAM*NPIX*NC)          // 714112 ; 173184 ints
#define OFF_CNT    (OFF_BINS + NPTS)                    // 887296 ; 16384 ints
#define OFF_CNT2   (OFF_CNT + NSPAT)                    // 903680 ; 16384 ints
#define OFF_OFFS   (OFF_CNT2 + NSPAT)                   // 920064 ; 16385 ints (pad 16400)
#define OFF_TLIST  (OFF_OFFS + 16400)                   // 936464 ; 173184 ints
#define OFF_WLIST  (OFF_TLIST + NPTS)                   // 1109648; 173184 floats
#define OFF_TMP    (OFF_WLIST + NPTS)                   // 1282832; 2097152 floats

// ---- exact fp32 LAPACK-emulating 3x3 inverse (sgetf2 + strti2 + sgetri) ----
__device__ void lapack_inv3(const float* src, float* dst) {
    float A[3][3]; int piv[3];
    for (int i = 0; i < 3; i++)
        for (int j = 0; j < 3; j++) A[i][j] = src[i*3+j];
    for (int j = 0; j < 3; j++) {
        int p = j; float mx = fabsf(A[j][j]);
        for (int i = j+1; i < 3; i++) { float v = fabsf(A[i][j]); if (v > mx) { mx = v; p = i; } }
        piv[j] = p;
        if (p != j) for (int k = 0; k < 3; k++) { float t = A[j][k]; A[j][k] = A[p][k]; A[p][k] = t; }
        float r = __fdiv_rn(1.0f, A[j][j]);
        for (int i = j+1; i < 3; i++) A[i][j] = __fmul_rn(A[i][j], r);
        for (int i = j+1; i < 3; i++)
            for (int k = j+1; k < 3; k++)
                A[i][k] = __fsub_rn(A[i][k], __fmul_rn(A[i][j], A[j][k]));
    }
    for (int j = 0; j < 3; j++) {
        float ajj = __fdiv_rn(1.0f, A[j][j]);
        A[j][j] = ajj;
        float najj = -ajj;
        for (int k = 0; k < j; k++) {
            float temp = A[k][j];
            for (int i = 0; i < k; i++) A[i][j] = __fadd_rn(A[i][j], __fmul_rn(temp, A[i][k]));
            A[k][j] = __fmul_rn(temp, A[k][k]);
        }
        for (int i = 0; i < j; i++) A[i][j] = __fmul_rn(A[i][j], najj);
    }
    float work[3];
    for (int j = 2; j >= 0; j--) {
        for (int i = j+1; i < 3; i++) { work[i] = A[i][j]; A[i][j] = 0.0f; }
        for (int k = j+1; k < 3; k++) {
            float t = -work[k];
            for (int i = 0; i < 3; i++) A[i][j] = __fadd_rn(A[i][j], __fmul_rn(t, A[i][k]));
        }
    }
    for (int j = 2; j >= 0; j--) {
        int p = piv[j];
        if (p != j) for (int i = 0; i < 3; i++) { float t = A[i][j]; A[i][j] = A[i][p]; A[i][p] = t; }
    }
    for (int i = 0; i < 3; i++)
        for (int j = 0; j < 3; j++) dst[i*3+j] = A[i][j];
}

__global__ void prep_kernel(const float* __restrict__ rots, const float* __restrict__ intrins,
                            const float* __restrict__ post_rots, float* __restrict__ mats) {
    int n = threadIdx.x;
    if (n >= NCAM) return;
    float invK[9], invP[9], M[9];
    lapack_inv3(intrins + n*9, invK);
    lapack_inv3(post_rots + n*9, invP);
    for (int i = 0; i < 3; i++)
        for (int k = 0; k < 3; k++) {
            float s = __fmul_rn(rots[n*9 + i*3 + 0], invK[0*3 + k]);
            s = __fadd_rn(s, __fmul_rn(rots[n*9 + i*3 + 1], invK[1*3 + k]));
            s = __fadd_rn(s, __fmul_rn(rots[n*9 + i*3 + 2], invK[2*3 + k]));
            M[i*3 + k] = s;
        }
    for (int i = 0; i < 9; i++) { mats[n*18 + i] = M[i]; mats[n*18 + 9 + i] = invP[i]; }
}

// ---- per-point voxel bin (exact fp32 replica) + per-voxel count ----
__global__ void bins_kernel(const float* __restrict__ trans, const float* __restrict__ post_trans,
                            const float* __restrict__ mats, int* __restrict__ bins,
                            int* __restrict__ cnt) {
    int p = blockIdx.x * 256 + threadIdx.x;
    if (p >= NPTS) return;
    int n   = p / (DB*NPIX);
    int rem = p % (DB*NPIX);
    int d   = rem / NPIX;
    int pix = rem % NPIX;
    int h = pix / FWW, w = pix % FWW;
    float xs = (float)((double)w * (703.0/43.0));
    float ys = (float)((double)h * (255.0/15.0));
    float ds = 4.0f + (float)d;
    const float* M = mats + n*18;
    const float* P = mats + n*18 + 9;
    float px = __fsub_rn(xs, post_trans[n*3+0]);
    float py = __fsub_rn(ys, post_trans[n*3+1]);
    float pz = __fsub_rn(ds, post_trans[n*3+2]);
    float q0 = __fadd_rn(__fadd_rn(__fmul_rn(P[0],px), __fmul_rn(P[1],py)), __fmul_rn(P[2],pz));
    float q1 = __fadd_rn(__fadd_rn(__fmul_rn(P[3],px), __fmul_rn(P[4],py)), __fmul_rn(P[5],pz));
    float q2 = __fadd_rn(__fadd_rn(__fmul_rn(P[6],px), __fmul_rn(P[7],py)), __fmul_rn(P[8],pz));
    float r0 = __fmul_rn(q0, q2);
    float r1 = __fmul_rn(q1, q2);
    float r2 = q2;
    float g0 = __fadd_rn(__fadd_rn(__fadd_rn(__fmul_rn(M[0],r0), __fmul_rn(M[1],r1)), __fmul_rn(M[2],r2)), trans[n*3+0]);
    float g1 = __fadd_rn(__fadd_rn(__fadd_rn(__fmul_rn(M[3],r0), __fmul_rn(M[4],r1)), __fmul_rn(M[5],r2)), trans[n*3+1]);
    float g2 = __fadd_rn(__fadd_rn(__fadd_rn(__fmul_rn(M[6],r0), __fmul_rn(M[7],r1)), __fmul_rn(M[8],r2)), trans[n*3+2]);
    const float lox = -50.8f - (0.8f/2.0f);
    const float loy = -50.8f - (0.8f/2.0f);
    const float loz =   0.0f - (20.0f/2.0f);
    int gx = (int)(__fdiv_rn(__fsub_rn(g0, lox), 0.8f));
    int gy = (int)(__fdiv_rn(__fsub_rn(g1, loy), 0.8f));
    int gz = (int)(__fdiv_rn(__fsub_rn(g2, loz), 20.0f));
    bool ok = (gx >= 0) & (gx < 128) & (gy >= 0) & (gy < 128) & (gz >= 0) & (gz < 1);
    int s = ok ? (gy*128 + gx) : -1;
    bins[p] = s;
    if (s >= 0) atomicAdd(&cnt[s], 1);
}

// ---- register-tiled GEMM: feat = w_depth @ x + b  (M=169 pad 192, N=704/cam, K=512) ----
// grid (11 pixtiles, 3 otiles, 6 cams), block 256 = 16x16; thread tile 4o x 4pix; KT=16 LDS-staged.
#define KT 16
__global__ __launch_bounds__(256) void feat_tiled(const float* __restrict__ x,
                                                  const float* __restrict__ wd,
                                                  const float* __restrict__ bd,
                                                  float* __restrict__ featd,
                                                  float* __restrict__ cfeatT) {
    __shared__ float xs[KT][64];
    __shared__ float wt[KT][64];
    int n  = blockIdx.z;
    int o0 = blockIdx.y * 64;
    int p0 = blockIdx.x * 64;
    int tid = threadIdx.x;
    int tx = tid & 15;        // pixel group
    int ty = tid >> 4;        // o group
    const float* xbase = x + (size_t)n * CIN * NPIX + p0;

    // x-tile load mapping: thread loads float4 at (k = tid>>4, px4 = (tid&15)*4)
    int lk  = tid >> 4;
    int px4 = (tid & 15) * 4;
    // w-tile load mapping: o = tid&63, kq = tid>>6
    int lo  = tid & 63;
    int lkq = tid >> 6;
    int orow = min(o0 + lo, 168);

    float acc[4][4];
    #pragma unroll
    for (int i = 0; i < 4; i++)
        #pragma unroll
        for (int j = 0; j < 4; j++) acc[i][j] = 0.0f;

    for (int c0 = 0; c0 < CIN; c0 += KT) {
        float4 xv = *(const float4*)(xbase + (size_t)(c0 + lk) * NPIX + px4);
        float4 wv = *(const float4*)(wd + (size_t)orow * CIN + c0 + lkq * 4);
        *(float4*)&xs[lk][px4] = xv;
        wt[lkq*4 + 0][lo] = wv.x;
        wt[lkq*4 + 1][lo] = wv.y;
        wt[lkq*4 + 2][lo] = wv.z;
        wt[lkq*4 + 3][lo] = wv.w;
        __syncthreads();
        #pragma unroll
        for (int k = 0; k < KT; k++) {
            float4 a = *(const float4*)&xs[k][tx*4];
            float4 b = *(const float4*)&wt[k][ty*4];
            acc[0][0] = fmaf(b.x, a.x, acc[0][0]);
            acc[0][1] = fmaf(b.x, a.y, acc[0][1]);
            acc[0][2] = fmaf(b.x, a.z, acc[0][2]);
            acc[0][3] = fmaf(b.x, a.w, acc[0][3]);
            acc[1][0] = fmaf(b.y, a.x, acc[1][0]);
            acc[1][1] = fmaf(b.y, a.y, acc[1][1]);
            acc[1][2] = fmaf(b.y, a.z, acc[1][2]);
            acc[1][3] = fmaf(b.y, a.w, acc[1][3]);
            acc[2][0] = fmaf(b.z, a.x, acc[2][0]);
            acc[2][1] = fmaf(b.z, a.y, acc[2][1]);
            acc[2][2] = fmaf(b.z, a.z, acc[2][2]);
            acc[2][3] = fmaf(b.z, a.w, acc[2][3]);
            acc[3][0] = fmaf(b.w, a.x, acc[3][0]);
            acc[3][1] = fmaf(b.w, a.y, acc[3][1]);
            acc[3][2] = fmaf(b.w, a.z, acc[3][2]);
            acc[3][3] = fmaf(b.w, a.w, acc[3][3]);
        }
        __syncthreads();
    }

    #pragma unroll
    for (int i = 0; i < 4; i++) {
        int o = o0 + ty*4 + i;
        if (o >= 169) continue;
        float b = bd[o];
        #pragma unroll
        for (int j = 0; j < 4; j++) {
            int pix = p0 + tx*4 + j;
            float v = __fadd_rn(acc[i][j], b);
            if (o < DB) featd[((size_t)n * DB + o) * NPIX + pix] = v;
            else        cfeatT[((size_t)(n * NPIX + pix)) * NC + (o - DB)] = v;
        }
    }
}

// ---- softmax over depth bins, in place ----
__global__ void softmax_kernel(float* __restrict__ featd) {
    int t = blockIdx.x * 256 + threadIdx.x;
    if (t >= TOTPIX) return;
    int n = t / NPIX, pix = t % NPIX;
    float* f = featd + (size_t)n * DB * NPIX + pix;
    float mx = -1e30f;
    float v[DB];
    #pragma unroll
    for (int d = 0; d < DB; d++) { v[d] = f[(size_t)d * NPIX]; mx = fmaxf(mx, v[d]); }
    float s = 0.0f;
    #pragma unroll
    for (int d = 0; d < DB; d++) { v[d] = expf(v[d] - mx); s += v[d]; }
    float inv = __fdiv_rn(1.0f, s);
    #pragma unroll
    for (int d = 0; d < DB; d++) f[(size_t)d * NPIX] = __fmul_rn(v[d], inv);
}

// ---- exclusive prefix over the 16384 voxel counts ----
__global__ void scan_kernel(const int* __restrict__ cnt, int* __restrict__ offsets) {
    __shared__ int sums[1024];
    int t = threadIdx.x;
    int vals[16];
    int run = 0;
    #pragma unroll
    for (int i = 0; i < 16; i++) { vals[i] = cnt[t*16 + i]; run += vals[i]; }
    sums[t] = run;
    __syncthreads();
    for (int off = 1; off < 1024; off <<= 1) {
        int u = (t >= off) ? sums[t - off] : 0;
        __syncthreads();
        sums[t] += u;
        __syncthreads();
    }
    int base = (t == 0) ? 0 : sums[t - 1];
    #pragma unroll
    for (int i = 0; i < 16; i++) { offsets[t*16 + i] = base; base += vals[i]; }
    if (t == 1023) offsets[NSPAT] = base;
}

// ---- fill per-voxel point lists (pixel id + softmaxed depth weight) ----
__global__ void fill_kernel(const int* __restrict__ bins, const float* __restrict__ featd,
                            const int* __restrict__ offsets, int* __restrict__ cnt2,
                            int* __restrict__ tlist, float* __restrict__ wlist) {
    int p = blockIdx.x * 256 + threadIdx.x;
    if (p >= NPTS) return;
    int s = bins[p];
    if (s < 0) return;
    int n   = p / (DB*NPIX);
    int rem = p % (DB*NPIX);
    int d   = rem / NPIX;
    int pix = rem % NPIX;
    float w = featd[((size_t)n * DB + d) * NPIX + pix];
    int pos = offsets[s] + atomicAdd(&cnt2[s], 1);
    tlist[pos] = n * NPIX + pix;
    wlist[pos] = w;
}

// ---- gather: one block per voxel, 128 threads = channels, no atomics ----
__global__ void gather_kernel(const int* __restrict__ offsets, const int* __restrict__ tlist,
                              const float* __restrict__ wlist, const float* __restrict__ cfeatT,
                              float* __restrict__ tmp) {
    int s = blockIdx.x;
    int c = threadIdx.x;
    int k   = offsets[s];
    int end = offsets[s + 1];
    float acc = 0.0f;
    for (; k + 1 < end; k += 2) {
        int   t0 = tlist[k],     t1 = tlist[k+1];
        float w0 = wlist[k],     w1 = wlist[k+1];
        float c0 = cfeatT[(size_t)t0 * NC + c];
        float c1 = cfeatT[(size_t)t1 * NC + c];
        acc = fmaf(w0, c0, acc);
        acc = fmaf(w1, c1, acc);
    }
    if (k < end) acc = fmaf(wlist[k], cfeatT[(size_t)tlist[k] * NC + c], acc);
    tmp[(size_t)s * NC + c] = acc;
}

// ---- transpose tmp[s][c] -> out[c][s] ----
__global__ void transpose_kernel(const float* __restrict__ tmp, float* __restrict__ out) {
    __shared__ float tile[32][33];
    int s0 = blockIdx.x * 32;
    int c0 = blockIdx.y * 32;
    int tx = threadIdx.x;
    int ty = threadIdx.y;
    #pragma unroll
    for (int i = 0; i < 32; i += 8)
        tile[ty + i][tx] = tmp[(size_t)(s0 + ty + i) * NC + c0 + tx];
    __syncthreads();
    #pragma unroll
    for (int i = 0; i < 32; i += 8)
        out[(size_t)(c0 + ty + i) * NSPAT + s0 + tx] = tile[tx][ty + i];
}

extern "C" void kernel_launch(void* const* d_in, const int* in_sizes, int n_in,
                              void* d_out, int out_size, void* d_ws, size_t ws_size,
                              hipStream_t stream) {
    const float* x          = (const float*)d_in[0];
    const float* rots       = (const float*)d_in[1];
    const float* trans      = (const float*)d_in[2];
    const float* intrins    = (const float*)d_in[3];
    const float* post_rots  = (const float*)d_in[4];
    const float* post_trans = (const float*)d_in[5];
    const float* w_depth    = (const float*)d_in[6];
    const float* b_depth    = (const float*)d_in[7];
    float* out = (float*)d_out;
    float* ws  = (float*)d_ws;

    float* mats    = ws + OFF_MATS;
    float* featd   = ws + OFF_FEATD;
    float* cfeatT  = ws + OFF_CFEATT;
    int*   bins    = (int*)(ws + OFF_BINS);
    int*   cnt     = (int*)(ws + OFF_CNT);
    int*   cnt2    = (int*)(ws + OFF_CNT2);
    int*   offsets = (int*)(ws + OFF_OFFS);
    int*   tlist   = (int*)(ws + OFF_TLIST);
    float* wlist   = ws + OFF_WLIST;
    float* tmp     = ws + OFF_TMP;

    // zero cnt + cnt2 (adjacent) in one shot
    hipMemsetAsync(cnt, 0, 2 * NSPAT * sizeof(int), stream);
    prep_kernel<<<1, 64, 0, stream>>>(rots, intrins, post_rots, mats);
    bins_kernel<<<(NPTS + 255) / 256, 256, 0, stream>>>(trans, post_trans, mats, bins, cnt);
    feat_tiled<<<dim3(11, 3, NCAM), 256, 0, stream>>>(x, w_depth, b_depth, featd, cfeatT);
    softmax_kernel<<<(TOTPIX + 255) / 256, 256, 0, stream>>>(featd);
    scan_kernel<<<1, 1024, 0, stream>>>(cnt, offsets);
    fill_kernel<<<(NPTS + 255) / 256, 256, 0, stream>>>(bins, featd, offsets, cnt2, tlist, wlist);
    gather_kernel<<<NSPAT, NC, 0, stream>>>(offsets, tlist, wlist, cfeatT, tmp);
    transpose_kernel<<<dim3(NSPAT / 32, NC / 32), dim3(32, 8), 0, stream>>>(tmp, out);
}

// Round 3
// 237.446 us; speedup vs baseline: 1.1720x; 1.0996x over previous
//
#include <hip/hip_runtime.h>
#include <math.h>

#define FHH 16
#define FWW 44
#define DB 41
#define NCAM 6
#define CIN 512
#define NC 128
#define NPIX (FHH*FWW)            // 704
#define TOTPIX (NCAM*NPIX)        // 4224
#define NPTS (NCAM*DB*NPIX)       // 173184
#define NSPAT (128*128)           // 16384
#define CHUNK 128

// workspace float offsets
#define OFF_MATS   0         // 256
#define OFF_BINS   256       // +173184 = 173440 (ints)
#define OFF_PLIST  173440    // +173184 = 346624 (ints)
#define OFF_WLIST  346624    // +173184 = 519808
#define OFF_ZERO   519808    // zeroed region starts here
#define OFF_FEATD  519808    // +173184 = 692992
#define OFF_CFEATT 692992    // +540672 = 1233664
#define OFF_CNT    1233664   // +16384 = 1250048 (ints)
#define OFF_CNT2   1250048   // +16384 = 1266432 (ints)
#define OFF_OFFS   1266432   // +16400 = 1282832 (ints)
#define OFF_TMP    1282832   // +2097152 = 3379984
#define ZERO_FLOATS (3379984 - OFF_ZERO)

// ---- exact fp32 LAPACK-emulating 3x3 inverse (sgetf2 + strti2 + sgetri) ----
__device__ void lapack_inv3(const float* src, float* dst) {
    float A[3][3]; int piv[3];
    for (int i = 0; i < 3; i++)
        for (int j = 0; j < 3; j++) A[i][j] = src[i*3+j];
    for (int j = 0; j < 3; j++) {
        int p = j; float mx = fabsf(A[j][j]);
        for (int i = j+1; i < 3; i++) { float v = fabsf(A[i][j]); if (v > mx) { mx = v; p = i; } }
        piv[j] = p;
        if (p != j) for (int k = 0; k < 3; k++) { float t = A[j][k]; A[j][k] = A[p][k]; A[p][k] = t; }
        float r = __fdiv_rn(1.0f, A[j][j]);
        for (int i = j+1; i < 3; i++) A[i][j] = __fmul_rn(A[i][j], r);
        for (int i = j+1; i < 3; i++)
            for (int k = j+1; k < 3; k++)
                A[i][k] = __fsub_rn(A[i][k], __fmul_rn(A[i][j], A[j][k]));
    }
    for (int j = 0; j < 3; j++) {
        float ajj = __fdiv_rn(1.0f, A[j][j]);
        A[j][j] = ajj;
        float najj = -ajj;
        for (int k = 0; k < j; k++) {
            float temp = A[k][j];
            for (int i = 0; i < k; i++) A[i][j] = __fadd_rn(A[i][j], __fmul_rn(temp, A[i][k]));
            A[k][j] = __fmul_rn(temp, A[k][k]);
        }
        for (int i = 0; i < j; i++) A[i][j] = __fmul_rn(A[i][j], najj);
    }
    float work[3];
    for (int j = 2; j >= 0; j--) {
        for (int i = j+1; i < 3; i++) { work[i] = A[i][j]; A[i][j] = 0.0f; }
        for (int k = j+1; k < 3; k++) {
            float t = -work[k];
            for (int i = 0; i < 3; i++) A[i][j] = __fadd_rn(A[i][j], __fmul_rn(t, A[i][k]));
        }
    }
    for (int j = 2; j >= 0; j--) {
        int p = piv[j];
        if (p != j) for (int i = 0; i < 3; i++) { float t = A[i][j]; A[i][j] = A[i][p]; A[i][p] = t; }
    }
    for (int i = 0; i < 3; i++)
        for (int j = 0; j < 3; j++) dst[i*3+j] = A[i][j];
}

__global__ void prep_kernel(const float* __restrict__ rots, const float* __restrict__ intrins,
                            const float* __restrict__ post_rots, float* __restrict__ mats) {
    int n = threadIdx.x;
    if (n >= NCAM) return;
    float invK[9], invP[9], M[9];
    lapack_inv3(intrins + n*9, invK);
    lapack_inv3(post_rots + n*9, invP);
    for (int i = 0; i < 3; i++)
        for (int k = 0; k < 3; k++) {
            float s = __fmul_rn(rots[n*9 + i*3 + 0], invK[0*3 + k]);
            s = __fadd_rn(s, __fmul_rn(rots[n*9 + i*3 + 1], invK[1*3 + k]));
            s = __fadd_rn(s, __fmul_rn(rots[n*9 + i*3 + 2], invK[2*3 + k]));
            M[i*3 + k] = s;
        }
    for (int i = 0; i < 9; i++) { mats[n*18 + i] = M[i]; mats[n*18 + 9 + i] = invP[i]; }
}

// ---- per-point voxel bin (exact fp32 replica) + wave-aggregated count ----
__global__ void bins_kernel(const float* __restrict__ trans, const float* __restrict__ post_trans,
                            const float* __restrict__ mats, int* __restrict__ bins,
                            int* __restrict__ cnt) {
    int p = blockIdx.x * 256 + threadIdx.x;
    int pc = p < NPTS ? p : NPTS - 1;
    int n   = pc / (DB*NPIX);
    int rem = pc % (DB*NPIX);
    int d   = rem / NPIX;
    int pix = rem % NPIX;
    int h = pix / FWW, w = pix % FWW;
    float xs = (float)((double)w * (703.0/43.0));
    float ys = (float)((double)h * (255.0/15.0));
    float ds = 4.0f + (float)d;
    const float* M = mats + n*18;
    const float* P = mats + n*18 + 9;
    float px = __fsub_rn(xs, post_trans[n*3+0]);
    float py = __fsub_rn(ys, post_trans[n*3+1]);
    float pz = __fsub_rn(ds, post_trans[n*3+2]);
    float q0 = __fadd_rn(__fadd_rn(__fmul_rn(P[0],px), __fmul_rn(P[1],py)), __fmul_rn(P[2],pz));
    float q1 = __fadd_rn(__fadd_rn(__fmul_rn(P[3],px), __fmul_rn(P[4],py)), __fmul_rn(P[5],pz));
    float q2 = __fadd_rn(__fadd_rn(__fmul_rn(P[6],px), __fmul_rn(P[7],py)), __fmul_rn(P[8],pz));
    float r0 = __fmul_rn(q0, q2);
    float r1 = __fmul_rn(q1, q2);
    float r2 = q2;
    float g0 = __fadd_rn(__fadd_rn(__fadd_rn(__fmul_rn(M[0],r0), __fmul_rn(M[1],r1)), __fmul_rn(M[2],r2)), trans[n*3+0]);
    float g1 = __fadd_rn(__fadd_rn(__fadd_rn(__fmul_rn(M[3],r0), __fmul_rn(M[4],r1)), __fmul_rn(M[5],r2)), trans[n*3+1]);
    float g2 = __fadd_rn(__fadd_rn(__fadd_rn(__fmul_rn(M[6],r0), __fmul_rn(M[7],r1)), __fmul_rn(M[8],r2)), trans[n*3+2]);
    const float lox = -50.8f - (0.8f/2.0f);
    const float loy = -50.8f - (0.8f/2.0f);
    const float loz =   0.0f - (20.0f/2.0f);
    int gx = (int)(__fdiv_rn(__fsub_rn(g0, lox), 0.8f));
    int gy = (int)(__fdiv_rn(__fsub_rn(g1, loy), 0.8f));
    int gz = (int)(__fdiv_rn(__fsub_rn(g2, loz), 20.0f));
    bool ok = (gx >= 0) & (gx < 128) & (gy >= 0) & (gy < 128) & (gz >= 0) & (gz < 1);
    int s = ok ? (gy*128 + gx) : -1;
    if (p < NPTS) bins[p] = s;
    bool valid = (p < NPTS) && (s >= 0);
    // wave-aggregated counting: one atomic per (wave, unique voxel)
    int lane = threadIdx.x & 63;
    unsigned long long todo = __ballot(valid);
    while (todo) {
        int lead = __builtin_ctzll(todo);
        int ls = __shfl(s, lead);
        unsigned long long match = __ballot(valid && (s == ls));
        if (valid && (s == ls)) {
            unsigned long long ltmask = (1ull << lane) - 1ull;
            int rank = __popcll(match & ltmask);
            if (rank == 0) atomicAdd(&cnt[ls], __popcll(match));
        }
        todo &= ~match;
    }
}

// ---- register-tiled GEMM with K-split x4: feat += w_depth[:,ks] @ x[ks] ----
// grid (11 pixtiles, 3 otiles, 6 cams * 4 ksplits), block 256 = 16x16; thread tile 4o x 4pix.
#define KT 16
__global__ __launch_bounds__(256) void feat_tiled(const float* __restrict__ x,
                                                  const float* __restrict__ wd,
                                                  const float* __restrict__ bd,
                                                  float* __restrict__ featd,
                                                  float* __restrict__ cfeatT) {
    __shared__ float xsm[KT][64];
    __shared__ float wt[KT][64];
    int n  = blockIdx.z >> 2;
    int ksp = blockIdx.z & 3;
    int o0 = blockIdx.y * 64;
    int p0 = blockIdx.x * 64;
    int tid = threadIdx.x;
    int tx = tid & 15;
    int ty = tid >> 4;
    const float* xbase = x + (size_t)n * CIN * NPIX + p0;

    int lk  = tid >> 4;
    int px4 = (tid & 15) * 4;
    int lo  = tid & 63;
    int lkq = tid >> 6;
    int orow = min(o0 + lo, 168);

    float acc[4][4];
    #pragma unroll
    for (int i = 0; i < 4; i++)
        #pragma unroll
        for (int j = 0; j < 4; j++) acc[i][j] = 0.0f;

    int cbeg = ksp * 128;
    for (int c0 = cbeg; c0 < cbeg + 128; c0 += KT) {
        float4 xv = *(const float4*)(xbase + (size_t)(c0 + lk) * NPIX + px4);
        float4 wv = *(const float4*)(wd + (size_t)orow * CIN + c0 + lkq * 4);
        *(float4*)&xsm[lk][px4] = xv;
        wt[lkq*4 + 0][lo] = wv.x;
        wt[lkq*4 + 1][lo] = wv.y;
        wt[lkq*4 + 2][lo] = wv.z;
        wt[lkq*4 + 3][lo] = wv.w;
        __syncthreads();
        #pragma unroll
        for (int k = 0; k < KT; k++) {
            float4 a = *(const float4*)&xsm[k][tx*4];
            float4 b = *(const float4*)&wt[k][ty*4];
            acc[0][0] = fmaf(b.x, a.x, acc[0][0]);
            acc[0][1] = fmaf(b.x, a.y, acc[0][1]);
            acc[0][2] = fmaf(b.x, a.z, acc[0][2]);
            acc[0][3] = fmaf(b.x, a.w, acc[0][3]);
            acc[1][0] = fmaf(b.y, a.x, acc[1][0]);
            acc[1][1] = fmaf(b.y, a.y, acc[1][1]);
            acc[1][2] = fmaf(b.y, a.z, acc[1][2]);
            acc[1][3] = fmaf(b.y, a.w, acc[1][3]);
            acc[2][0] = fmaf(b.z, a.x, acc[2][0]);
            acc[2][1] = fmaf(b.z, a.y, acc[2][1]);
            acc[2][2] = fmaf(b.z, a.z, acc[2][2]);
            acc[2][3] = fmaf(b.z, a.w, acc[2][3]);
            acc[3][0] = fmaf(b.w, a.x, acc[3][0]);
            acc[3][1] = fmaf(b.w, a.y, acc[3][1]);
            acc[3][2] = fmaf(b.w, a.z, acc[3][2]);
            acc[3][3] = fmaf(b.w, a.w, acc[3][3]);
        }
        __syncthreads();
    }

    #pragma unroll
    for (int i = 0; i < 4; i++) {
        int o = o0 + ty*4 + i;
        if (o >= 169) continue;
        float b = (ksp == 0) ? bd[o] : 0.0f;
        #pragma unroll
        for (int j = 0; j < 4; j++) {
            int pix = p0 + tx*4 + j;
            float v = __fadd_rn(acc[i][j], b);
            if (o < DB) atomicAdd(&featd[((size_t)n * DB + o) * NPIX + pix], v);
            else        atomicAdd(&cfeatT[((size_t)(n * NPIX + pix)) * NC + (o - DB)], v);
        }
    }
}

// ---- softmax over depth bins, in place ----
__global__ void softmax_kernel(float* __restrict__ featd) {
    int t = blockIdx.x * 256 + threadIdx.x;
    if (t >= TOTPIX) return;
    int n = t / NPIX, pix = t % NPIX;
    float* f = featd + (size_t)n * DB * NPIX + pix;
    float mx = -1e30f;
    float v[DB];
    #pragma unroll
    for (int d = 0; d < DB; d++) { v[d] = f[(size_t)d * NPIX]; mx = fmaxf(mx, v[d]); }
    float s = 0.0f;
    #pragma unroll
    for (int d = 0; d < DB; d++) { v[d] = expf(v[d] - mx); s += v[d]; }
    float inv = __fdiv_rn(1.0f, s);
    #pragma unroll
    for (int d = 0; d < DB; d++) f[(size_t)d * NPIX] = __fmul_rn(v[d], inv);
}

// ---- exclusive prefix over the 16384 voxel counts ----
__global__ void scan_kernel(const int* __restrict__ cnt, int* __restrict__ offsets) {
    __shared__ int sums[1024];
    int t = threadIdx.x;
    int vals[16];
    int run = 0;
    #pragma unroll
    for (int i = 0; i < 16; i++) { vals[i] = cnt[t*16 + i]; run += vals[i]; }
    sums[t] = run;
    __syncthreads();
    for (int off = 1; off < 1024; off <<= 1) {
        int u = (t >= off) ? sums[t - off] : 0;
        __syncthreads();
        sums[t] += u;
        __syncthreads();
    }
    int base = (t == 0) ? 0 : sums[t - 1];
    #pragma unroll
    for (int i = 0; i < 16; i++) { offsets[t*16 + i] = base; base += vals[i]; }
    if (t == 1023) offsets[NSPAT] = base;
}

// ---- fill per-voxel point lists; wave-aggregated position atomics ----
__global__ void fill_kernel(const int* __restrict__ bins, const float* __restrict__ featd,
                            const int* __restrict__ offsets, int* __restrict__ cnt2,
                            int* __restrict__ plist, float* __restrict__ wlist) {
    int p = blockIdx.x * 256 + threadIdx.x;
    int pc = p < NPTS ? p : NPTS - 1;
    int s = bins[pc];
    bool valid = (p < NPTS) && (s >= 0);
    int n   = pc / (DB*NPIX);
    int rem = pc % (DB*NPIX);
    int d   = rem / NPIX;
    int pix = rem % NPIX;
    int lane = threadIdx.x & 63;
    int pos = 0;
    unsigned long long todo = __ballot(valid);
    while (todo) {
        int lead = __builtin_ctzll(todo);
        int ls = __shfl(s, lead);
        unsigned long long match = __ballot(valid && (s == ls));
        if (valid && (s == ls)) {
            unsigned long long ltmask = (1ull << lane) - 1ull;
            int rank = __popcll(match & ltmask);
            int basep = 0;
            if (rank == 0) basep = atomicAdd(&cnt2[ls], __popcll(match));
            basep = __shfl(basep, lead);
            pos = offsets[ls] + basep + rank;
        }
        todo &= ~match;
    }
    if (valid) {
        float w = featd[((size_t)n * DB + d) * NPIX + pix];
        plist[pos] = (s << 13) | (n * NPIX + pix);
        wlist[pos] = w;
    }
}

// ---- load-balanced chunked gather: one block per 128-point chunk ----
__global__ void gather_kernel(const int* __restrict__ offsets, const int* __restrict__ plist,
                              const float* __restrict__ wlist, const float* __restrict__ cfeatT,
                              float* __restrict__ tmp) {
    __shared__ int keys[CHUNK];
    __shared__ float wts[CHUNK];
    int T = offsets[NSPAT];
    int base = blockIdx.x * CHUNK;
    if (base >= T) return;
    int end = min(base + CHUNK, T);
    int m = end - base;
    int c = threadIdx.x;        // channel 0..127
    if (c < m) { keys[c] = plist[base + c]; wts[c] = wlist[base + c]; }
    __syncthreads();
    float acc = 0.0f;
    int cur = keys[0] >> 13;
    for (int i = 0; i < m; i++) {
        int key = keys[i];
        int s = key >> 13;
        if (s != cur) {
            bool span = (offsets[cur] < base) || (offsets[cur + 1] > end);
            if (span) atomicAdd(&tmp[(size_t)cur * NC + c], acc);
            else      tmp[(size_t)cur * NC + c] = acc;
            acc = 0.0f;
            cur = s;
        }
        acc = fmaf(wts[i], cfeatT[(size_t)(key & 0x1FFF) * NC + c], acc);
    }
    bool span = (offsets[cur] < base) || (offsets[cur + 1] > end);
    if (span) atomicAdd(&tmp[(size_t)cur * NC + c], acc);
    else      tmp[(size_t)cur * NC + c] = acc;
}

// ---- transpose tmp[s][c] -> out[c][s] ----
__global__ void transpose_kernel(const float* __restrict__ tmp, float* __restrict__ out) {
    __shared__ float tile[32][33];
    int s0 = blockIdx.x * 32;
    int c0 = blockIdx.y * 32;
    int tx = threadIdx.x;
    int ty = threadIdx.y;
    #pragma unroll
    for (int i = 0; i < 32; i += 8)
        tile[ty + i][tx] = tmp[(size_t)(s0 + ty + i) * NC + c0 + tx];
    __syncthreads();
    #pragma unroll
    for (int i = 0; i < 32; i += 8)
        out[(size_t)(c0 + ty + i) * NSPAT + s0 + tx] = tile[tx][ty + i];
}

extern "C" void kernel_launch(void* const* d_in, const int* in_sizes, int n_in,
                              void* d_out, int out_size, void* d_ws, size_t ws_size,
                              hipStream_t stream) {
    const float* x          = (const float*)d_in[0];
    const float* rots       = (const float*)d_in[1];
    const float* trans      = (const float*)d_in[2];
    const float* intrins    = (const float*)d_in[3];
    const float* post_rots  = (const float*)d_in[4];
    const float* post_trans = (const float*)d_in[5];
    const float* w_depth    = (const float*)d_in[6];
    const float* b_depth    = (const float*)d_in[7];
    float* out = (float*)d_out;
    float* ws  = (float*)d_ws;

    float* mats    = ws + OFF_MATS;
    int*   bins    = (int*)(ws + OFF_BINS);
    int*   plist   = (int*)(ws + OFF_PLIST);
    float* wlist   = ws + OFF_WLIST;
    float* featd   = ws + OFF_FEATD;
    float* cfeatT  = ws + OFF_CFEATT;
    int*   cnt     = (int*)(ws + OFF_CNT);
    int*   cnt2    = (int*)(ws + OFF_CNT2);
    int*   offsets = (int*)(ws + OFF_OFFS);
    float* tmp     = ws + OFF_TMP;

    // zero featd, cfeatT, cnt, cnt2, offsets, tmp in one contiguous memset
    hipMemsetAsync(ws + OFF_ZERO, 0, (size_t)ZERO_FLOATS * sizeof(float), stream);
    prep_kernel<<<1, 64, 0, stream>>>(rots, intrins, post_rots, mats);
    bins_kernel<<<(NPTS + 255) / 256, 256, 0, stream>>>(trans, post_trans, mats, bins, cnt);
    feat_tiled<<<dim3(11, 3, NCAM * 4), 256, 0, stream>>>(x, w_depth, b_depth, featd, cfeatT);
    softmax_kernel<<<(TOTPIX + 255) / 256, 256, 0, stream>>>(featd);
    scan_kernel<<<1, 1024, 0, stream>>>(cnt, offsets);
    fill_kernel<<<(NPTS + 255) / 256, 256, 0, stream>>>(bins, featd, offsets, cnt2, plist, wlist);
    gather_kernel<<<(NPTS + CHUNK - 1) / CHUNK, NC, 0, stream>>>(offsets, plist, wlist, cfeatT, tmp);
    transpose_kernel<<<dim3(NSPAT / 32, NC / 32), dim3(32, 8), 0, stream>>>(tmp, out);
}

// Round 4
// 190.184 us; speedup vs baseline: 1.4633x; 1.2485x over previous
//
#include <hip/hip_runtime.h>
#include <math.h>

#define FHH 16
#define FWW 44
#define DB 41
#define NCAM 6
#define CIN 512
#define NC 128
#define NPIX (FHH*FWW)            // 704
#define TOTPIX (NCAM*NPIX)        // 4224
#define NPTS (NCAM*DB*NPIX)       // 173184
#define NSPAT (128*128)           // 16384
#define CHUNK 128
#define MOUT 169                  // 41 depth + 128 context
#define PARTSZ (NCAM*MOUT*NPIX)   // 713856 per k-split

// workspace float offsets
#define OFF_MATS   0                          // 256
#define OFF_BINS   256                        // +173184
#define OFF_PLIST  (OFF_BINS + NPTS)          // 173440
#define OFF_WLIST  (OFF_PLIST + NPTS)         // 346624
#define OFF_PART   (OFF_WLIST + NPTS)         // 519808 ; 4*713856 = 2855424
#define OFF_TMP    OFF_PART                   // alias: tmp (2097152) reuses part after fuse
#define OFF_FEATD  (OFF_PART + 4*PARTSZ)      // 3375232 ; +173184
#define OFF_CFEATT (OFF_FEATD + NCAM*DB*NPIX) // 3548416 ; +540672
#define OFF_OFFS   (OFF_CFEATT + TOTPIX*NC)   // 4089088 ; 16400 ints
#define OFF_CNT    (OFF_OFFS + 16400)         // 4105488 ; 16384
#define OFF_CNT2   (OFF_CNT + NSPAT)          // 4121872 ; 16384 -> total 4138256 floats (~16.6MB)

// ---- exact fp32 LAPACK-emulating 3x3 inverse (sgetf2 + strti2 + sgetri) ----
__device__ void lapack_inv3(const float* src, float* dst) {
    float A[3][3]; int piv[3];
    for (int i = 0; i < 3; i++)
        for (int j = 0; j < 3; j++) A[i][j] = src[i*3+j];
    for (int j = 0; j < 3; j++) {
        int p = j; float mx = fabsf(A[j][j]);
        for (int i = j+1; i < 3; i++) { float v = fabsf(A[i][j]); if (v > mx) { mx = v; p = i; } }
        piv[j] = p;
        if (p != j) for (int k = 0; k < 3; k++) { float t = A[j][k]; A[j][k] = A[p][k]; A[p][k] = t; }
        float r = __fdiv_rn(1.0f, A[j][j]);
        for (int i = j+1; i < 3; i++) A[i][j] = __fmul_rn(A[i][j], r);
        for (int i = j+1; i < 3; i++)
            for (int k = j+1; k < 3; k++)
                A[i][k] = __fsub_rn(A[i][k], __fmul_rn(A[i][j], A[j][k]));
    }
    for (int j = 0; j < 3; j++) {
        float ajj = __fdiv_rn(1.0f, A[j][j]);
        A[j][j] = ajj;
        float najj = -ajj;
        for (int k = 0; k < j; k++) {
            float temp = A[k][j];
            for (int i = 0; i < k; i++) A[i][j] = __fadd_rn(A[i][j], __fmul_rn(temp, A[i][k]));
            A[k][j] = __fmul_rn(temp, A[k][k]);
        }
        for (int i = 0; i < j; i++) A[i][j] = __fmul_rn(A[i][j], najj);
    }
    float work[3];
    for (int j = 2; j >= 0; j--) {
        for (int i = j+1; i < 3; i++) { work[i] = A[i][j]; A[i][j] = 0.0f; }
        for (int k = j+1; k < 3; k++) {
            float t = -work[k];
            for (int i = 0; i < 3; i++) A[i][j] = __fadd_rn(A[i][j], __fmul_rn(t, A[i][k]));
        }
    }
    for (int j = 2; j >= 0; j--) {
        int p = piv[j];
        if (p != j) for (int i = 0; i < 3; i++) { float t = A[i][j]; A[i][j] = A[i][p]; A[i][p] = t; }
    }
    for (int i = 0; i < 3; i++)
        for (int j = 0; j < 3; j++) dst[i*3+j] = A[i][j];
}

__global__ void prep_kernel(const float* __restrict__ rots, const float* __restrict__ intrins,
                            const float* __restrict__ post_rots, float* __restrict__ mats) {
    int n = threadIdx.x;
    if (n >= NCAM) return;
    float invK[9], invP[9], M[9];
    lapack_inv3(intrins + n*9, invK);
    lapack_inv3(post_rots + n*9, invP);
    for (int i = 0; i < 3; i++)
        for (int k = 0; k < 3; k++) {
            float s = __fmul_rn(rots[n*9 + i*3 + 0], invK[0*3 + k]);
            s = __fadd_rn(s, __fmul_rn(rots[n*9 + i*3 + 1], invK[1*3 + k]));
            s = __fadd_rn(s, __fmul_rn(rots[n*9 + i*3 + 2], invK[2*3 + k]));
            M[i*3 + k] = s;
        }
    for (int i = 0; i < 9; i++) { mats[n*18 + i] = M[i]; mats[n*18 + 9 + i] = invP[i]; }
}

// ---- per-point voxel bin (exact fp32 replica) + wave-aggregated count ----
__global__ void bins_kernel(const float* __restrict__ trans, const float* __restrict__ post_trans,
                            const float* __restrict__ mats, int* __restrict__ bins,
                            int* __restrict__ cnt) {
    int p = blockIdx.x * 256 + threadIdx.x;
    int pc = p < NPTS ? p : NPTS - 1;
    int n   = pc / (DB*NPIX);
    int rem = pc % (DB*NPIX);
    int d   = rem / NPIX;
    int pix = rem % NPIX;
    int h = pix / FWW, w = pix % FWW;
    float xs = (float)((double)w * (703.0/43.0));
    float ys = (float)((double)h * (255.0/15.0));
    float ds = 4.0f + (float)d;
    const float* M = mats + n*18;
    const float* P = mats + n*18 + 9;
    float px = __fsub_rn(xs, post_trans[n*3+0]);
    float py = __fsub_rn(ys, post_trans[n*3+1]);
    float pz = __fsub_rn(ds, post_trans[n*3+2]);
    float q0 = __fadd_rn(__fadd_rn(__fmul_rn(P[0],px), __fmul_rn(P[1],py)), __fmul_rn(P[2],pz));
    float q1 = __fadd_rn(__fadd_rn(__fmul_rn(P[3],px), __fmul_rn(P[4],py)), __fmul_rn(P[5],pz));
    float q2 = __fadd_rn(__fadd_rn(__fmul_rn(P[6],px), __fmul_rn(P[7],py)), __fmul_rn(P[8],pz));
    float r0 = __fmul_rn(q0, q2);
    float r1 = __fmul_rn(q1, q2);
    float r2 = q2;
    float g0 = __fadd_rn(__fadd_rn(__fadd_rn(__fmul_rn(M[0],r0), __fmul_rn(M[1],r1)), __fmul_rn(M[2],r2)), trans[n*3+0]);
    float g1 = __fadd_rn(__fadd_rn(__fadd_rn(__fmul_rn(M[3],r0), __fmul_rn(M[4],r1)), __fmul_rn(M[5],r2)), trans[n*3+1]);
    float g2 = __fadd_rn(__fadd_rn(__fadd_rn(__fmul_rn(M[6],r0), __fmul_rn(M[7],r1)), __fmul_rn(M[8],r2)), trans[n*3+2]);
    const float lox = -50.8f - (0.8f/2.0f);
    const float loy = -50.8f - (0.8f/2.0f);
    const float loz =   0.0f - (20.0f/2.0f);
    int gx = (int)(__fdiv_rn(__fsub_rn(g0, lox), 0.8f));
    int gy = (int)(__fdiv_rn(__fsub_rn(g1, loy), 0.8f));
    int gz = (int)(__fdiv_rn(__fsub_rn(g2, loz), 20.0f));
    bool ok = (gx >= 0) & (gx < 128) & (gy >= 0) & (gy < 128) & (gz >= 0) & (gz < 1);
    int s = ok ? (gy*128 + gx) : -1;
    if (p < NPTS) bins[p] = s;
    bool valid = (p < NPTS) && (s >= 0);
    int lane = threadIdx.x & 63;
    unsigned long long todo = __ballot(valid);
    while (todo) {
        int lead = __builtin_ctzll(todo);
        int ls = __shfl(s, lead);
        unsigned long long match = __ballot(valid && (s == ls));
        if (valid && (s == ls)) {
            unsigned long long ltmask = (1ull << lane) - 1ull;
            int rank = __popcll(match & ltmask);
            if (rank == 0) atomicAdd(&cnt[ls], __popcll(match));
        }
        todo &= ~match;
    }
}

// ---- register-tiled GEMM, K-split x4, coalesced float4 partial stores ----
#define KT 16
__global__ __launch_bounds__(256) void feat_part(const float* __restrict__ x,
                                                 const float* __restrict__ wd,
                                                 float* __restrict__ part) {
    __shared__ float xsm[KT][64];
    __shared__ float wt[KT][64];
    int n   = blockIdx.z >> 2;
    int ksp = blockIdx.z & 3;
    int o0 = blockIdx.y * 64;
    int p0 = blockIdx.x * 64;
    int tid = threadIdx.x;
    int tx = tid & 15;
    int ty = tid >> 4;
    const float* xbase = x + (size_t)n * CIN * NPIX + p0;

    int lk  = tid >> 4;
    int px4 = (tid & 15) * 4;
    int lo  = tid & 63;
    int lkq = tid >> 6;
    int orow = min(o0 + lo, MOUT - 1);

    float acc[4][4];
    #pragma unroll
    for (int i = 0; i < 4; i++)
        #pragma unroll
        for (int j = 0; j < 4; j++) acc[i][j] = 0.0f;

    int cbeg = ksp * 128;
    for (int c0 = cbeg; c0 < cbeg + 128; c0 += KT) {
        float4 xv = *(const float4*)(xbase + (size_t)(c0 + lk) * NPIX + px4);
        float4 wv = *(const float4*)(wd + (size_t)orow * CIN + c0 + lkq * 4);
        *(float4*)&xsm[lk][px4] = xv;
        wt[lkq*4 + 0][lo] = wv.x;
        wt[lkq*4 + 1][lo] = wv.y;
        wt[lkq*4 + 2][lo] = wv.z;
        wt[lkq*4 + 3][lo] = wv.w;
        __syncthreads();
        #pragma unroll
        for (int k = 0; k < KT; k++) {
            float4 a = *(const float4*)&xsm[k][tx*4];
            float4 b = *(const float4*)&wt[k][ty*4];
            acc[0][0] = fmaf(b.x, a.x, acc[0][0]);
            acc[0][1] = fmaf(b.x, a.y, acc[0][1]);
            acc[0][2] = fmaf(b.x, a.z, acc[0][2]);
            acc[0][3] = fmaf(b.x, a.w, acc[0][3]);
            acc[1][0] = fmaf(b.y, a.x, acc[1][0]);
            acc[1][1] = fmaf(b.y, a.y, acc[1][1]);
            acc[1][2] = fmaf(b.y, a.z, acc[1][2]);
            acc[1][3] = fmaf(b.y, a.w, acc[1][3]);
            acc[2][0] = fmaf(b.z, a.x, acc[2][0]);
            acc[2][1] = fmaf(b.z, a.y, acc[2][1]);
            acc[2][2] = fmaf(b.z, a.z, acc[2][2]);
            acc[2][3] = fmaf(b.z, a.w, acc[2][3]);
            acc[3][0] = fmaf(b.w, a.x, acc[3][0]);
            acc[3][1] = fmaf(b.w, a.y, acc[3][1]);
            acc[3][2] = fmaf(b.w, a.z, acc[3][2]);
            acc[3][3] = fmaf(b.w, a.w, acc[3][3]);
        }
        __syncthreads();
    }

    // coalesced float4 stores: part[((ksp*6+n)*169+o)*704 + p0 + tx*4]
    float* pb = part + ((size_t)(ksp * NCAM + n) * MOUT) * NPIX + p0 + tx*4;
    #pragma unroll
    for (int i = 0; i < 4; i++) {
        int o = ty*4 + i + o0;
        if (o >= MOUT) continue;
        float4 v = make_float4(acc[i][0], acc[i][1], acc[i][2], acc[i][3]);
        *(float4*)(pb + (size_t)o * NPIX) = v;
    }
}

// ---- fuse: reduce 4 partials + bias, softmax depth bins, transpose context ----
// grid TOTPIX/32 = 132 blocks, block 128 = 32 pix x 4 o-slices (o = ty + 4*i)
#define RPIX 32
__global__ __launch_bounds__(128) void fuse_kernel(const float* __restrict__ part,
                                                   const float* __restrict__ bd,
                                                   float* __restrict__ featd,
                                                   float* __restrict__ cfeatT) {
    __shared__ float red[8][RPIX];
    __shared__ float ctile[RPIX][129];
    int px = threadIdx.x & 31;
    int ty = threadIdx.x >> 5;
    int gpix = blockIdx.x * RPIX + px;
    int n  = gpix / NPIX;
    int pp = gpix % NPIX;
    const float* pbase = part + ((size_t)n * MOUT) * NPIX + pp;

    float v[43];
    #pragma unroll
    for (int i = 0; i < 43; i++) {
        int o = ty + 4*i;
        if (o < MOUT) {
            const float* p = pbase + (size_t)o * NPIX;
            float s = __fadd_rn(__fadd_rn(__fadd_rn(p[0], p[PARTSZ]), p[2*PARTSZ]), p[3*PARTSZ]);
            v[i] = __fadd_rn(s, bd[o]);
        }
    }
    // softmax over o < 41
    float pmax = -1e30f;
    #pragma unroll
    for (int i = 0; i < 43; i++) { int o = ty + 4*i; if (o < DB) pmax = fmaxf(pmax, v[i]); }
    red[ty][px] = pmax;
    __syncthreads();
    float m = fmaxf(fmaxf(red[0][px], red[1][px]), fmaxf(red[2][px], red[3][px]));
    float psum = 0.0f;
    #pragma unroll
    for (int i = 0; i < 43; i++) {
        int o = ty + 4*i;
        if (o < DB) { v[i] = expf(v[i] - m); psum += v[i]; }
    }
    red[4 + ty][px] = psum;
    __syncthreads();
    float tot = __fadd_rn(__fadd_rn(__fadd_rn(red[4][px], red[5][px]), red[6][px]), red[7][px]);
    float inv = __fdiv_rn(1.0f, tot);
    #pragma unroll
    for (int i = 0; i < 43; i++) {
        int o = ty + 4*i;
        if (o < DB)        featd[((size_t)n * DB + o) * NPIX + pp] = __fmul_rn(v[i], inv);
        else if (o < MOUT) ctile[px][o - DB] = v[i];
    }
    __syncthreads();
    // coalesced cfeatT[pix][c] stores
    int pixbase = blockIdx.x * RPIX;
    #pragma unroll
    for (int r = 0; r < 32; r++) {
        int idx = threadIdx.x + 128 * r;     // 0..4095
        int row = idx >> 7;                   // 0..31
        int c   = idx & 127;
        cfeatT[(size_t)(pixbase + row) * NC + c] = ctile[row][c];
    }
}

// ---- exclusive prefix over the 16384 voxel counts ----
__global__ void scan_kernel(const int* __restrict__ cnt, int* __restrict__ offsets) {
    __shared__ int sums[1024];
    int t = threadIdx.x;
    int vals[16];
    int run = 0;
    #pragma unroll
    for (int i = 0; i < 16; i++) { vals[i] = cnt[t*16 + i]; run += vals[i]; }
    sums[t] = run;
    __syncthreads();
    for (int off = 1; off < 1024; off <<= 1) {
        int u = (t >= off) ? sums[t - off] : 0;
        __syncthreads();
        sums[t] += u;
        __syncthreads();
    }
    int base = (t == 0) ? 0 : sums[t - 1];
    #pragma unroll
    for (int i = 0; i < 16; i++) { offsets[t*16 + i] = base; base += vals[i]; }
    if (t == 1023) offsets[NSPAT] = base;
}

// ---- fill per-voxel point lists; wave-aggregated position atomics ----
__global__ void fill_kernel(const int* __restrict__ bins, const float* __restrict__ featd,
                            const int* __restrict__ offsets, int* __restrict__ cnt2,
                            int* __restrict__ plist, float* __restrict__ wlist) {
    int p = blockIdx.x * 256 + threadIdx.x;
    int pc = p < NPTS ? p : NPTS - 1;
    int s = bins[pc];
    bool valid = (p < NPTS) && (s >= 0);
    int n   = pc / (DB*NPIX);
    int rem = pc % (DB*NPIX);
    int d   = rem / NPIX;
    int pix = rem % NPIX;
    int lane = threadIdx.x & 63;
    int pos = 0;
    unsigned long long todo = __ballot(valid);
    while (todo) {
        int lead = __builtin_ctzll(todo);
        int ls = __shfl(s, lead);
        unsigned long long match = __ballot(valid && (s == ls));
        if (valid && (s == ls)) {
            unsigned long long ltmask = (1ull << lane) - 1ull;
            int rank = __popcll(match & ltmask);
            int basep = 0;
            if (rank == 0) basep = atomicAdd(&cnt2[ls], __popcll(match));
            basep = __shfl(basep, lead);
            pos = offsets[ls] + basep + rank;
        }
        todo &= ~match;
    }
    if (valid) {
        float w = featd[((size_t)n * DB + d) * NPIX + pix];
        plist[pos] = (s << 13) | (n * NPIX + pix);
        wlist[pos] = w;
    }
}

// ---- load-balanced chunked gather: one block per 128-point chunk ----
__global__ void gather_kernel(const int* __restrict__ offsets, const int* __restrict__ plist,
                              const float* __restrict__ wlist, const float* __restrict__ cfeatT,
                              float* __restrict__ tmp) {
    __shared__ int keys[CHUNK];
    __shared__ float wts[CHUNK];
    int T = offsets[NSPAT];
    int base = blockIdx.x * CHUNK;
    if (base >= T) return;
    int end = min(base + CHUNK, T);
    int m = end - base;
    int c = threadIdx.x;
    if (c < m) { keys[c] = plist[base + c]; wts[c] = wlist[base + c]; }
    __syncthreads();
    float acc = 0.0f;
    int cur = keys[0] >> 13;
    for (int i = 0; i < m; i++) {
        int key = keys[i];
        int s = key >> 13;
        if (s != cur) {
            bool span = (offsets[cur] < base) || (offsets[cur + 1] > end);
            if (span) atomicAdd(&tmp[(size_t)cur * NC + c], acc);
            else      tmp[(size_t)cur * NC + c] = acc;
            acc = 0.0f;
            cur = s;
        }
        acc = fmaf(wts[i], cfeatT[(size_t)(key & 0x1FFF) * NC + c], acc);
    }
    bool span = (offsets[cur] < base) || (offsets[cur + 1] > end);
    if (span) atomicAdd(&tmp[(size_t)cur * NC + c], acc);
    else      tmp[(size_t)cur * NC + c] = acc;
}

// ---- transpose tmp[s][c] -> out[c][s] ----
__global__ void transpose_kernel(const float* __restrict__ tmp, float* __restrict__ out) {
    __shared__ float tile[32][33];
    int s0 = blockIdx.x * 32;
    int c0 = blockIdx.y * 32;
    int tx = threadIdx.x;
    int ty = threadIdx.y;
    #pragma unroll
    for (int i = 0; i < 32; i += 8)
        tile[ty + i][tx] = tmp[(size_t)(s0 + ty + i) * NC + c0 + tx];
    __syncthreads();
    #pragma unroll
    for (int i = 0; i < 32; i += 8)
        out[(size_t)(c0 + ty + i) * NSPAT + s0 + tx] = tile[tx][ty + i];
}

extern "C" void kernel_launch(void* const* d_in, const int* in_sizes, int n_in,
                              void* d_out, int out_size, void* d_ws, size_t ws_size,
                              hipStream_t stream) {
    const float* x          = (const float*)d_in[0];
    const float* rots       = (const float*)d_in[1];
    const float* trans      = (const float*)d_in[2];
    const float* intrins    = (const float*)d_in[3];
    const float* post_rots  = (const float*)d_in[4];
    const float* post_trans = (const float*)d_in[5];
    const float* w_depth    = (const float*)d_in[6];
    const float* b_depth    = (const float*)d_in[7];
    float* out = (float*)d_out;
    float* ws  = (float*)d_ws;

    float* mats    = ws + OFF_MATS;
    int*   bins    = (int*)(ws + OFF_BINS);
    int*   plist   = (int*)(ws + OFF_PLIST);
    float* wlist   = ws + OFF_WLIST;
    float* part    = ws + OFF_PART;
    float* featd   = ws + OFF_FEATD;
    float* cfeatT  = ws + OFF_CFEATT;
    int*   offsets = (int*)(ws + OFF_OFFS);
    int*   cnt     = (int*)(ws + OFF_CNT);
    int*   cnt2    = (int*)(ws + OFF_CNT2);
    float* tmp     = ws + OFF_TMP;   // aliases part

    hipMemsetAsync(cnt, 0, 2 * NSPAT * sizeof(int), stream);   // cnt + cnt2
    prep_kernel<<<1, 64, 0, stream>>>(rots, intrins, post_rots, mats);
    bins_kernel<<<(NPTS + 255) / 256, 256, 0, stream>>>(trans, post_trans, mats, bins, cnt);
    feat_part<<<dim3(11, 3, NCAM * 4), 256, 0, stream>>>(x, w_depth, part);
    fuse_kernel<<<TOTPIX / RPIX, 128, 0, stream>>>(part, b_depth, featd, cfeatT);
    scan_kernel<<<1, 1024, 0, stream>>>(cnt, offsets);
    fill_kernel<<<(NPTS + 255) / 256, 256, 0, stream>>>(bins, featd, offsets, cnt2, plist, wlist);
    hipMemsetAsync(tmp, 0, (size_t)NSPAT * NC * sizeof(float), stream);  // after fuse: tmp aliases part
    gather_kernel<<<(NPTS + CHUNK - 1) / CHUNK, NC, 0, stream>>>(offsets, plist, wlist, cfeatT, tmp);
    transpose_kernel<<<dim3(NSPAT / 32, NC / 32), dim3(32, 8), 0, stream>>>(tmp, out);
}